// Round 2
// baseline (1110.471 us; speedup 1.0000x reference)
//
#include <hip/hip_runtime.h>
#include <math.h>

#define NN 50000
#define NE 800000
#define NTILE 12500   // NE / 64

typedef __bf16 bf16x4 __attribute__((ext_vector_type(4)));
typedef __bf16 bf16x8 __attribute__((ext_vector_type(8)));
typedef float  f32x4  __attribute__((ext_vector_type(4)));

__device__ __forceinline__ float softplus_f(float v) {
    return fmaxf(v, 0.f) + log1pf(expf(-fabsf(v)));
}

// ---------------- CSR build ----------------
__global__ void k_zero(int* deg) {
    int i = blockIdx.x * blockDim.x + threadIdx.x;
    if (i < NN) deg[i] = 0;
}

__global__ void k_hist(const int* __restrict__ ei, int* __restrict__ deg) {
    int e = blockIdx.x * blockDim.x + threadIdx.x;
    if (e < NE) atomicAdd(&deg[ei[NE + e]], 1);
}

// single-block scan over 50000 degrees -> rowptr (exclusive-from-0) + cursor copy
__global__ void k_scan(const int* __restrict__ deg, int* __restrict__ rowptr,
                       int* __restrict__ cursor) {
    __shared__ int wsum[16];
    __shared__ int woff[16];
    __shared__ int carry_s;
    const int tid = threadIdx.x;
    const int lane = tid & 63, wid = tid >> 6;
    if (tid == 0) { carry_s = 0; rowptr[0] = 0; }
    __syncthreads();
    for (int base = 0; base < NN; base += 1024) {
        const int i = base + tid;
        int v = (i < NN) ? deg[i] : 0;
        int s = v;
        #pragma unroll
        for (int off = 1; off < 64; off <<= 1) {
            int t = __shfl_up(s, off);
            if (lane >= off) s += t;
        }
        if (lane == 63) wsum[wid] = s;
        __syncthreads();
        if (tid == 0) {
            int a = carry_s;
            #pragma unroll
            for (int q = 0; q < 16; ++q) { woff[q] = a; a += wsum[q]; }
            carry_s = a;
        }
        __syncthreads();
        const int incl = s + woff[wid];
        if (i < NN) { rowptr[i + 1] = incl; cursor[i] = incl - v; }
        __syncthreads();
    }
}

__global__ void k_scatter(const int* __restrict__ ei, int* __restrict__ cursor,
                          int* __restrict__ eidx) {
    int e = blockIdx.x * blockDim.x + threadIdx.x;
    if (e < NE) {
        int d = ei[NE + e];
        int p = atomicAdd(&cursor[d], 1);
        eidx[p] = e;
    }
}

// ---------------- edge kernel: strain + msg GEMM + edge GEMM ----------------
// A layout per edge row (k-index): [0..63]=x_src  [64..127]=x_dst
// [128..191]=edge_attr  [192]=strain  [193..223]=ZEROED pad (NaN*0=NaN --
// uninitialized LDS here poisoned the MFMA on each block's first tile in R1).
// Weights staged TRANSPOSED (k-contiguous per output column) to match the
// B-fragment (n=lane&15, k=quad*8+j -> 16B contiguous ds_read_b128).
__global__ __launch_bounds__(256, 2) void k_edge(
    const float* __restrict__ x, const int* __restrict__ ei,
    const float* __restrict__ ea, const float* __restrict__ r2,
    const float* __restrict__ dinit, const float* __restrict__ Wmsg,
    const float* __restrict__ bmsg, const float* __restrict__ Wedge,
    const float* __restrict__ bedge,
    float* __restrict__ out_edge, float* __restrict__ out_msg,
    float* __restrict__ out_strain)
{
    __shared__ __bf16 sWm[64 * 232];   // Wmsg^T, row n, stride 232 (464B: 16B-aligned, 8-way bank spread)
    __shared__ __bf16 sWe[64 * 88];    // Wedge^T, row n, stride 88 (176B)
    __shared__ __bf16 sA [64 * 232];   // 64 edge rows, stride 232
    __shared__ int sSrc[64];
    __shared__ int sDst[64];

    const int tid  = threadIdx.x;
    const int lane = tid & 63;
    const int wid  = tid >> 6;     // wave 0..3, owns edges wid*16..wid*16+15
    const int col  = lane & 15;
    const int quad = lane >> 4;

    // ---- stage transposed weights once per (persistent) block ----
    {
        const int n = tid & 63, kg = tid >> 6;
        for (int k = kg; k < 232; k += 4) {
            float v = 0.f;
            if (k < 128)       v = Wmsg[k * 64 + n];         // x_j | x_i rows
            else if (k < 192)  v = Wmsg[(k + 1) * 64 + n];   // edge_attr rows 129..192
            else if (k == 192) v = Wmsg[128 * 64 + n];       // strain row
            sWm[n * 232 + k] = (__bf16)v;                    // k>=193: 0
        }
        for (int k = kg; k < 64; k += 4)
            sWe[n * 88 + k] = (__bf16)Wedge[k * 64 + n];
    }
    float bm[4], be[4];
    #pragma unroll
    for (int nt = 0; nt < 4; ++nt) {
        bm[nt] = bmsg[nt * 16 + col];
        be[nt] = bedge[nt * 16 + col];
    }

    for (int tile = blockIdx.x; tile < NTILE; tile += gridDim.x) {
        const int e0 = tile * 64;
        if (tid < 64) { sSrc[tid] = ei[e0 + tid]; sDst[tid] = ei[NE + e0 + tid]; }
        __syncthreads();

        // ---- stage A (gathers, float4 -> bf16x4) ----
        #pragma unroll
        for (int rr = 0; rr < 4; ++rr) {
            const int i = tid + rr * 256;      // 0..1023
            const int e = i >> 4, c = i & 15;  // 64 edges x 16 float4-chunks
            const float4 xj = *(const float4*)(x + (size_t)sSrc[e] * 64 + c * 4);
            const float4 xi = *(const float4*)(x + (size_t)sDst[e] * 64 + c * 4);
            const float4 ev = *(const float4*)(ea + (size_t)(e0 + e) * 64 + c * 4);
            bf16x4 a, b, d;
            a[0]=(__bf16)xj.x; a[1]=(__bf16)xj.y; a[2]=(__bf16)xj.z; a[3]=(__bf16)xj.w;
            b[0]=(__bf16)xi.x; b[1]=(__bf16)xi.y; b[2]=(__bf16)xi.z; b[3]=(__bf16)xi.w;
            d[0]=(__bf16)ev.x; d[1]=(__bf16)ev.y; d[2]=(__bf16)ev.z; d[3]=(__bf16)ev.w;
            *(bf16x4*)&sA[e * 232 +       c * 4] = a;
            *(bf16x4*)&sA[e * 232 +  64 + c * 4] = b;
            *(bf16x4*)&sA[e * 232 + 128 + c * 4] = d;
        }
        if (tid < 64) {
            const float rx = r2[(size_t)(e0 + tid) * 2];
            const float ry = r2[(size_t)(e0 + tid) * 2 + 1];
            const float di = dinit[e0 + tid];
            const float st = (sqrtf(rx * rx + ry * ry) - di) / di;
            // k=192 strain, k=193..223 zero pad (MUST be written: NaN*0=NaN)
            bf16x8 p0 = {};
            p0[0] = (__bf16)st;
            const bf16x8 z = {};
            *(bf16x8*)&sA[tid * 232 + 192] = p0;
            *(bf16x8*)&sA[tid * 232 + 200] = z;
            *(bf16x8*)&sA[tid * 232 + 208] = z;
            *(bf16x8*)&sA[tid * 232 + 216] = z;
            out_strain[e0 + tid] = st;
        }
        __syncthreads();

        // ---- msg = softplus(A @ Wm + b) : 7 k-chunks x 4 n-tiles ----
        f32x4 acc[4];
        #pragma unroll
        for (int nt = 0; nt < 4; ++nt) acc[nt] = (f32x4){0.f, 0.f, 0.f, 0.f};
        const int abase = (wid * 16 + col) * 232 + quad * 8;
        #pragma unroll
        for (int kc = 0; kc < 7; ++kc) {
            const bf16x8 af = *(const bf16x8*)&sA[abase + kc * 32];
            #pragma unroll
            for (int nt = 0; nt < 4; ++nt) {
                const bf16x8 bfr = *(const bf16x8*)&sWm[(nt * 16 + col) * 232 + kc * 32 + quad * 8];
                acc[nt] = __builtin_amdgcn_mfma_f32_16x16x32_bf16(af, bfr, acc[nt], 0, 0, 0);
            }
        }

        // epilogue: softplus, write msg (fp32), store bf16 msg into wave-local A2 overlay
        __bf16* A2 = &sA[wid * 16 * 232];   // wave-private region, stride 88
        #pragma unroll
        for (int nt = 0; nt < 4; ++nt) {
            #pragma unroll
            for (int rg = 0; rg < 4; ++rg) {
                const int row = quad * 4 + rg;
                const float sp = softplus_f(acc[nt][rg] + bm[nt]);
                out_msg[(size_t)(e0 + wid * 16 + row) * 64 + nt * 16 + col] = sp;
                A2[row * 88 + nt * 16 + col] = (__bf16)sp;
            }
        }
        __syncthreads();   // make A2 visible before fragment reads

        // ---- edge_new = msg @ We + b : 2 k-chunks x 4 n-tiles ----
        f32x4 acc2[4];
        #pragma unroll
        for (int nt = 0; nt < 4; ++nt) acc2[nt] = (f32x4){0.f, 0.f, 0.f, 0.f};
        #pragma unroll
        for (int kc = 0; kc < 2; ++kc) {
            const bf16x8 af = *(const bf16x8*)&A2[col * 88 + kc * 32 + quad * 8];
            #pragma unroll
            for (int nt = 0; nt < 4; ++nt) {
                const bf16x8 bfr = *(const bf16x8*)&sWe[(nt * 16 + col) * 88 + kc * 32 + quad * 8];
                acc2[nt] = __builtin_amdgcn_mfma_f32_16x16x32_bf16(af, bfr, acc2[nt], 0, 0, 0);
            }
        }
        #pragma unroll
        for (int nt = 0; nt < 4; ++nt) {
            #pragma unroll
            for (int rg = 0; rg < 4; ++rg) {
                out_edge[(size_t)(e0 + wid * 16 + quad * 4 + rg) * 64 + nt * 16 + col]
                    = acc2[nt][rg] + be[nt];
            }
        }
        __syncthreads();   // protect sA/sSrc before next tile's staging
    }
}

// ---------------- node kernel: mean-agg (CSR gather) + update GEMM ----------------
__global__ __launch_bounds__(256) void k_node(
    const float* __restrict__ x, const float* __restrict__ msg,
    const int* __restrict__ rowptr, const int* __restrict__ eidx,
    const float* __restrict__ Wupd, const float* __restrict__ bupd,
    float* __restrict__ out_x)
{
    __shared__ float sW[128 * 64];
    const int tid = threadIdx.x;
    for (int i = tid; i < 2048; i += 256)
        ((float4*)sW)[i] = ((const float4*)Wupd)[i];
    __syncthreads();

    const int lane = tid & 63, wid = tid >> 6;
    const int n = blockIdx.x * 4 + wid;          // 12500 * 4 = 50000 exact
    const int rs = rowptr[n], ren = rowptr[n + 1];

    float acc = 0.f;
    for (int j = rs; j < ren; ++j) {
        const int e = eidx[j];
        acc += msg[(size_t)e * 64 + lane];       // coalesced 256B row per wave
    }
    const float mean = acc / fmaxf((float)(ren - rs), 1.f);
    const float xr = x[(size_t)n * 64 + lane];

    float o = bupd[lane];
    #pragma unroll 16
    for (int k = 0; k < 64; ++k)
        o += __shfl(xr, k) * sW[k * 64 + lane];
    #pragma unroll 16
    for (int k = 0; k < 64; ++k)
        o += __shfl(mean, k) * sW[(64 + k) * 64 + lane];

    out_x[(size_t)n * 64 + lane] = o;
}

extern "C" void kernel_launch(void* const* d_in, const int* in_sizes, int n_in,
                              void* d_out, int out_size, void* d_ws, size_t ws_size,
                              hipStream_t stream) {
    const float* x     = (const float*)d_in[0];
    const int*   ei    = (const int*)d_in[1];
    const float* ea    = (const float*)d_in[2];
    const float* r2    = (const float*)d_in[3];
    const float* dinit = (const float*)d_in[4];
    const float* Wmsg  = (const float*)d_in[5];
    const float* bmsg  = (const float*)d_in[6];
    const float* Wupd  = (const float*)d_in[7];
    const float* bupd  = (const float*)d_in[8];
    const float* Wedge = (const float*)d_in[9];
    const float* bedge = (const float*)d_in[10];

    float* out_x      = (float*)d_out;                 // [50000,64]
    float* out_edge   = out_x + (size_t)NN * 64;       // [800000,64]
    float* out_msg    = out_edge + (size_t)NE * 64;    // [800000,64]
    float* out_strain = out_msg + (size_t)NE * 64;     // [800000,1]

    int* deg    = (int*)d_ws;          // 50000
    int* rowptr = deg + 50176;         // 50001
    int* cursor = rowptr + 50304;      // 50000
    int* eidx   = cursor + 50176;      // 800000   (total ~3.8 MB of ws)

    k_zero   <<<196,   256,  0, stream>>>(deg);
    k_hist   <<<3125,  256,  0, stream>>>(ei, deg);
    k_scan   <<<1,     1024, 0, stream>>>(deg, rowptr, cursor);
    k_scatter<<<3125,  256,  0, stream>>>(ei, cursor, eidx);
    k_edge   <<<512,   256,  0, stream>>>(x, ei, ea, r2, dinit, Wmsg, bmsg,
                                          Wedge, bedge, out_edge, out_msg, out_strain);
    k_node   <<<12500, 256,  0, stream>>>(x, out_msg, rowptr, eidx, Wupd, bupd, out_x);
}